// Round 1
// baseline (933.722 us; speedup 1.0000x reference)
//
#include <hip/hip_runtime.h>

// GCN 2-layer forward on MI355X.
// d_in: [0]=x (N*128 f32), [1]=edge_index (2*E i32), [2]=W1 (128*64),
//       [3]=b1 (64), [4]=W2 (64*40), [5]=b2 (40)
// d_out: N*40 f32

#define FIN 128
#define H1  64
#define C2  40

// ---------- degree / norm ----------
__global__ void k_count(const int* __restrict__ col, int E, int* __restrict__ deg) {
    int e = blockIdx.x * blockDim.x + threadIdx.x;
    if (e < E) atomicAdd(&deg[col[e]], 1);
}

__global__ void k_dinv(const int* __restrict__ deg, float* __restrict__ dinv, int N) {
    int i = blockIdx.x * blockDim.x + threadIdx.x;
    if (i < N) dinv[i] = rsqrtf((float)deg[i] + 1.0f);  // +1 self-loop; always > 0
}

// ---------- GEMM1: h1 = x @ W1  (N x 128) @ (128 x 64) ----------
// block = 256 threads = 4 nodes * 64 outputs. W1 (32 KB) + 4 x-rows (2 KB) in LDS.
__global__ __launch_bounds__(256) void k_gemm1(const float* __restrict__ x,
                                               const float* __restrict__ W1,
                                               float* __restrict__ h1, int N) {
    __shared__ float Ws[FIN * H1];     // 32 KB
    __shared__ float xs[4][FIN];       // 2 KB
    int t = threadIdx.x;
    for (int i = t; i < FIN * H1; i += 256) Ws[i] = W1[i];
    int node0 = blockIdx.x * 4;
    for (int i = t; i < 4 * FIN; i += 256) {
        int n = i >> 7, k = i & 127;
        int node = node0 + n; if (node >= N) node = N - 1;
        xs[n][k] = x[(long long)node * FIN + k];
    }
    __syncthreads();
    int n = t >> 6, o = t & 63;
    float acc = 0.f;
#pragma unroll 8
    for (int k = 0; k < FIN; ++k) acc += xs[n][k] * Ws[k * H1 + o];
    int node = node0 + n;
    if (node < N) h1[(long long)node * H1 + o] = acc;
}

// ---------- init agg1 = dinv^2 * h1 + b1  (self-loop + bias fused) ----------
__global__ void k_init1(const float* __restrict__ h1, const float* __restrict__ dinv,
                        const float* __restrict__ b1, float* __restrict__ agg, int N) {
    int idx = blockIdx.x * blockDim.x + threadIdx.x;
    if (idx < N * H1) {
        int i = idx >> 6, f = idx & 63;
        float d = dinv[i];
        agg[idx] = d * d * h1[idx] + b1[f];
    }
}

// ---------- edge scatter layer 1: agg[c] += dinv[r]*dinv[c]*h1[r] ----------
__global__ void k_edge1(const int* __restrict__ row, const int* __restrict__ col,
                        const float* __restrict__ dinv, const float* __restrict__ h1,
                        float* __restrict__ agg, int E) {
    int idx = blockIdx.x * blockDim.x + threadIdx.x;  // E*64 = 102.4M < 2^31
    if (idx >= E * H1) return;
    int e = idx >> 6, f = idx & 63;
    int r = row[e], c = col[e];
    float norm = dinv[r] * dinv[c];
    atomicAdd(&agg[c * H1 + f], norm * h1[r * H1 + f]);
}

// ---------- GEMM2: g = relu(agg1) @ W2  (N x 64) @ (64 x 40) ----------
// block = 320 threads = 8 nodes * 40 outputs. ReLU fused into LDS load.
__global__ __launch_bounds__(320) void k_gemm2(const float* __restrict__ agg1,
                                               const float* __restrict__ W2,
                                               float* __restrict__ g, int N) {
    __shared__ float Ws[H1 * C2];      // 10 KB
    __shared__ float hs[8][H1];        // 2 KB
    int t = threadIdx.x;
    for (int i = t; i < H1 * C2; i += 320) Ws[i] = W2[i];
    int node0 = blockIdx.x * 8;
    for (int i = t; i < 8 * H1; i += 320) {
        int n = i >> 6, k = i & 63;
        int node = node0 + n; if (node >= N) node = N - 1;
        hs[n][k] = fmaxf(agg1[(long long)node * H1 + k], 0.f);
    }
    __syncthreads();
    int n = t / C2, c = t % C2;        // t < 320 -> n < 8
    float acc = 0.f;
#pragma unroll 8
    for (int k = 0; k < H1; ++k) acc += hs[n][k] * Ws[k * C2 + c];
    int node = node0 + n;
    if (node < N) g[(long long)node * C2 + c] = acc;
}

// ---------- init out = dinv^2 * g + b2 ----------
__global__ void k_init2(const float* __restrict__ g, const float* __restrict__ dinv,
                        const float* __restrict__ b2, float* __restrict__ out, int N) {
    int idx = blockIdx.x * blockDim.x + threadIdx.x;
    if (idx < N * C2) {
        int i = idx / C2, f = idx % C2;
        float d = dinv[i];
        out[idx] = d * d * g[idx] + b2[f];
    }
}

// ---------- edge scatter layer 2: out[c] += dinv[r]*dinv[c]*g[r] ----------
__global__ void k_edge2(const int* __restrict__ row, const int* __restrict__ col,
                        const float* __restrict__ dinv, const float* __restrict__ g,
                        float* __restrict__ out, int E) {
    int idx = blockIdx.x * blockDim.x + threadIdx.x;  // E*40 = 64M
    if (idx >= E * C2) return;
    int e = idx / C2, f = idx % C2;
    int r = row[e], c = col[e];
    float norm = dinv[r] * dinv[c];
    atomicAdd(&out[c * C2 + f], norm * g[r * C2 + f]);
}

extern "C" void kernel_launch(void* const* d_in, const int* in_sizes, int n_in,
                              void* d_out, int out_size, void* d_ws, size_t ws_size,
                              hipStream_t stream) {
    const float* x   = (const float*)d_in[0];
    const int*   ei  = (const int*)d_in[1];
    const float* W1  = (const float*)d_in[2];
    const float* b1  = (const float*)d_in[3];
    const float* W2  = (const float*)d_in[4];
    const float* b2  = (const float*)d_in[5];
    float* out = (float*)d_out;

    const int N = in_sizes[0] / FIN;       // 100000
    const int E = in_sizes[1] / 2;         // 1600000
    const int* row = ei;
    const int* col = ei + E;

    // workspace layout (fp32 elems): deg[N](int), dinv[N], h1[N*64], agg1[N*64], g[N*40]
    int*   deg  = (int*)d_ws;
    float* dinv = (float*)d_ws + N;
    float* h1   = (float*)d_ws + 2 * N;
    float* agg1 = h1 + (size_t)N * H1;
    float* g    = agg1 + (size_t)N * H1;

    hipMemsetAsync(deg, 0, (size_t)N * sizeof(int), stream);

    k_count<<<(E + 255) / 256, 256, 0, stream>>>(col, E, deg);
    k_dinv<<<(N + 255) / 256, 256, 0, stream>>>(deg, dinv, N);

    // layer 1
    k_gemm1<<<(N + 3) / 4, 256, 0, stream>>>(x, W1, h1, N);
    k_init1<<<((long long)N * H1 + 255) / 256, 256, 0, stream>>>(h1, dinv, b1, agg1, N);
    k_edge1<<<((long long)E * H1 + 255) / 256, 256, 0, stream>>>(row, col, dinv, h1, agg1, E);

    // layer 2 (ReLU fused into GEMM2 load)
    k_gemm2<<<(N + 7) / 8, 320, 0, stream>>>(agg1, W2, g, N);
    k_init2<<<((long long)N * C2 + 255) / 256, 256, 0, stream>>>(g, dinv, b2, out, N);
    k_edge2<<<((long long)E * C2 + 255) / 256, 256, 0, stream>>>(row, col, dinv, g, out, E);
}

// Round 2
// 527.075 us; speedup vs baseline: 1.7715x; 1.7715x over previous
//
#include <hip/hip_runtime.h>

// GCN 2-layer forward on MI355X — CSR gather-aggregation (no fp32 scatter atomics).
// d_in: [0]=x (N*128 f32), [1]=edge_index (2*E i32), [2]=W1 (128*64),
//       [3]=b1 (64), [4]=W2 (64*40), [5]=b2 (40)
// d_out: N*40 f32

#define FIN 128
#define H1  64
#define C2  40

// ---------- degree ----------
__global__ void k_count(const int* __restrict__ col, int E, int* __restrict__ deg) {
    int e = blockIdx.x * blockDim.x + threadIdx.x;
    if (e < E) atomicAdd(&deg[col[e]], 1);
}

__global__ void k_dinv(const int* __restrict__ deg, float* __restrict__ dinv, int N) {
    int i = blockIdx.x * blockDim.x + threadIdx.x;
    if (i < N) dinv[i] = rsqrtf((float)deg[i] + 1.0f);  // +1 self-loop
}

// ---------- 3-kernel exclusive scan of deg -> rowptr ----------
__global__ __launch_bounds__(256) void k_scanA(const int* __restrict__ deg,
                                               int* __restrict__ rowptr,
                                               int* __restrict__ bsum, int N) {
    __shared__ int s[256];
    int i = blockIdx.x * 256 + threadIdx.x;
    int v = (i < N) ? deg[i] : 0;
    s[threadIdx.x] = v;
    __syncthreads();
    for (int off = 1; off < 256; off <<= 1) {
        int t = (threadIdx.x >= off) ? s[threadIdx.x - off] : 0;
        __syncthreads();
        s[threadIdx.x] += t;
        __syncthreads();
    }
    if (i < N) rowptr[i] = s[threadIdx.x] - v;  // exclusive
    if (threadIdx.x == 255) bsum[blockIdx.x] = s[255];
}

__global__ __launch_bounds__(512) void k_scanB(int* __restrict__ bsum, int nb) {
    __shared__ int s[512];
    int t = threadIdx.x;
    int v = (t < nb) ? bsum[t] : 0;
    s[t] = v;
    __syncthreads();
    for (int off = 1; off < 512; off <<= 1) {
        int u = (t >= off) ? s[t - off] : 0;
        __syncthreads();
        s[t] += u;
        __syncthreads();
    }
    if (t < nb) bsum[t] = s[t] - v;  // exclusive over block sums
}

__global__ void k_scanC(int* __restrict__ rowptr, const int* __restrict__ bsum, int N) {
    int i = blockIdx.x * blockDim.x + threadIdx.x;
    if (i < N) rowptr[i] += bsum[i >> 8];
}

// ---------- CSR fill: esrc[pos]=row, ew[pos]=dinv[r]*dinv[c] ----------
__global__ void k_fill(const int* __restrict__ row, const int* __restrict__ col,
                       const int* __restrict__ rowptr, int* __restrict__ cursor,
                       const float* __restrict__ dinv,
                       int* __restrict__ esrc, float* __restrict__ ew, int E) {
    int e = blockIdx.x * blockDim.x + threadIdx.x;
    if (e >= E) return;
    int r = row[e], c = col[e];
    int pos = rowptr[c] + atomicAdd(&cursor[c], 1);
    esrc[pos] = r;
    ew[pos] = dinv[r] * dinv[c];
}

// ---------- GEMM1: h1 = x @ W1  (N x 128) @ (128 x 64) ----------
__global__ __launch_bounds__(256) void k_gemm1(const float* __restrict__ x,
                                               const float* __restrict__ W1,
                                               float* __restrict__ h1, int N) {
    __shared__ float Ws[FIN * H1];     // 32 KB
    __shared__ float xs[4][FIN];       // 2 KB
    int t = threadIdx.x;
    for (int i = t; i < FIN * H1; i += 256) Ws[i] = W1[i];
    int node0 = blockIdx.x * 4;
    for (int i = t; i < 4 * FIN; i += 256) {
        int n = i >> 7, k = i & 127;
        int node = node0 + n; if (node >= N) node = N - 1;
        xs[n][k] = x[(long long)node * FIN + k];
    }
    __syncthreads();
    int n = t >> 6, o = t & 63;
    float acc = 0.f;
#pragma unroll 8
    for (int k = 0; k < FIN; ++k) acc += xs[n][k] * Ws[k * H1 + o];
    int node = node0 + n;
    if (node < N) h1[(long long)node * H1 + o] = acc;
}

// ---------- agg1: one wave per node, lane = feature (64) ----------
// agg1[c,f] = dinv[c]^2*h1[c,f] + b1[f] + sum_e ew[e]*h1[src[e],f]
__global__ __launch_bounds__(256) void k_agg1(const int* __restrict__ rowptr,
                                              const int* __restrict__ deg,
                                              const int* __restrict__ esrc,
                                              const float* __restrict__ ew,
                                              const float* __restrict__ h1,
                                              const float* __restrict__ dinv,
                                              const float* __restrict__ b1,
                                              float* __restrict__ agg, int N) {
    int w = (blockIdx.x * blockDim.x + threadIdx.x) >> 6;  // node
    int lane = threadIdx.x & 63;
    if (w >= N) return;
    int start = rowptr[w], d = deg[w];
    float dc = dinv[w];
    float acc = dc * dc * h1[w * H1 + lane];  // self-loop
    int i = 0;
    for (; i + 4 <= d; i += 4) {
        int e = start + i;
        int r0 = esrc[e], r1 = esrc[e + 1], r2 = esrc[e + 2], r3 = esrc[e + 3];
        float w0 = ew[e], w1 = ew[e + 1], w2 = ew[e + 2], w3 = ew[e + 3];
        float v0 = h1[r0 * H1 + lane], v1 = h1[r1 * H1 + lane];
        float v2 = h1[r2 * H1 + lane], v3 = h1[r3 * H1 + lane];
        acc += w0 * v0 + w1 * v1 + w2 * v2 + w3 * v3;
    }
    for (; i < d; ++i) {
        int e = start + i;
        acc += ew[e] * h1[esrc[e] * H1 + lane];
    }
    agg[w * H1 + lane] = acc + b1[lane];
}

// ---------- GEMM2: g = relu(agg1) @ W2  (N x 64) @ (64 x 40) ----------
__global__ __launch_bounds__(320) void k_gemm2(const float* __restrict__ agg1,
                                               const float* __restrict__ W2,
                                               float* __restrict__ g, int N) {
    __shared__ float Ws[H1 * C2];      // 10 KB
    __shared__ float hs[8][H1];        // 2 KB
    int t = threadIdx.x;
    for (int i = t; i < H1 * C2; i += 320) Ws[i] = W2[i];
    int node0 = blockIdx.x * 8;
    for (int i = t; i < 8 * H1; i += 320) {
        int n = i >> 6, k = i & 63;
        int node = node0 + n; if (node >= N) node = N - 1;
        hs[n][k] = fmaxf(agg1[(long long)node * H1 + k], 0.f);
    }
    __syncthreads();
    int n = t / C2, c = t % C2;
    float acc = 0.f;
#pragma unroll 8
    for (int k = 0; k < H1; ++k) acc += hs[n][k] * Ws[k * C2 + c];
    int node = node0 + n;
    if (node < N) g[(long long)node * C2 + c] = acc;
}

// ---------- agg2: one wave per node, lanes 0..39 = features ----------
__global__ __launch_bounds__(256) void k_agg2(const int* __restrict__ rowptr,
                                              const int* __restrict__ deg,
                                              const int* __restrict__ esrc,
                                              const float* __restrict__ ew,
                                              const float* __restrict__ g,
                                              const float* __restrict__ dinv,
                                              const float* __restrict__ b2,
                                              float* __restrict__ out, int N) {
    int w = (blockIdx.x * blockDim.x + threadIdx.x) >> 6;  // node
    int lane = threadIdx.x & 63;
    if (w >= N || lane >= C2) return;
    int start = rowptr[w], d = deg[w];
    float dc = dinv[w];
    float acc = dc * dc * g[w * C2 + lane];  // self-loop
    int i = 0;
    for (; i + 4 <= d; i += 4) {
        int e = start + i;
        int r0 = esrc[e], r1 = esrc[e + 1], r2 = esrc[e + 2], r3 = esrc[e + 3];
        float w0 = ew[e], w1 = ew[e + 1], w2 = ew[e + 2], w3 = ew[e + 3];
        float v0 = g[r0 * C2 + lane], v1 = g[r1 * C2 + lane];
        float v2 = g[r2 * C2 + lane], v3 = g[r3 * C2 + lane];
        acc += w0 * v0 + w1 * v1 + w2 * v2 + w3 * v3;
    }
    for (; i < d; ++i) {
        int e = start + i;
        acc += ew[e] * g[esrc[e] * C2 + lane];
    }
    out[w * C2 + lane] = acc + b2[lane];
}

extern "C" void kernel_launch(void* const* d_in, const int* in_sizes, int n_in,
                              void* d_out, int out_size, void* d_ws, size_t ws_size,
                              hipStream_t stream) {
    const float* x   = (const float*)d_in[0];
    const int*   ei  = (const int*)d_in[1];
    const float* W1  = (const float*)d_in[2];
    const float* b1  = (const float*)d_in[3];
    const float* W2  = (const float*)d_in[4];
    const float* b2  = (const float*)d_in[5];
    float* out = (float*)d_out;

    const int N = in_sizes[0] / FIN;       // 100000
    const int E = in_sizes[1] / 2;         // 1600000
    const int* row = ei;
    const int* col = ei + E;

    // workspace layout (4-byte elems)
    char* ws = (char*)d_ws;
    size_t off = 0;
    int*   deg    = (int*)(ws + off);   off += (size_t)N * 4;
    int*   rowptr = (int*)(ws + off);   off += (size_t)N * 4;
    int*   cursor = (int*)(ws + off);   off += (size_t)N * 4;
    int*   bsum   = (int*)(ws + off);   off += 512 * 4;
    float* dinv   = (float*)(ws + off); off += (size_t)N * 4;
    int*   esrc   = (int*)(ws + off);   off += (size_t)E * 4;
    float* ew     = (float*)(ws + off); off += (size_t)E * 4;
    float* h1     = (float*)(ws + off); off += (size_t)N * H1 * 4;
    float* agg1   = (float*)(ws + off); off += (size_t)N * H1 * 4;
    float* g      = (float*)(ws + off); off += (size_t)N * C2 * 4;

    hipMemsetAsync(deg, 0, (size_t)N * sizeof(int), stream);
    hipMemsetAsync(cursor, 0, (size_t)N * sizeof(int), stream);

    k_count<<<(E + 255) / 256, 256, 0, stream>>>(col, E, deg);
    k_dinv<<<(N + 255) / 256, 256, 0, stream>>>(deg, dinv, N);

    // exclusive scan deg -> rowptr
    int nb = (N + 255) / 256;             // 391
    k_scanA<<<nb, 256, 0, stream>>>(deg, rowptr, bsum, N);
    k_scanB<<<1, 512, 0, stream>>>(bsum, nb);
    k_scanC<<<(N + 255) / 256, 256, 0, stream>>>(rowptr, bsum, N);

    k_fill<<<(E + 255) / 256, 256, 0, stream>>>(row, col, rowptr, cursor, dinv, esrc, ew, E);

    // layer 1
    k_gemm1<<<(N + 3) / 4, 256, 0, stream>>>(x, W1, h1, N);
    k_agg1<<<((size_t)N * 64 + 255) / 256, 256, 0, stream>>>(rowptr, deg, esrc, ew, h1, dinv, b1, agg1, N);

    // layer 2 (ReLU fused into GEMM2 load)
    k_gemm2<<<(N + 7) / 8, 320, 0, stream>>>(agg1, W2, g, N);
    k_agg2<<<((size_t)N * 64 + 255) / 256, 256, 0, stream>>>(rowptr, deg, esrc, ew, g, dinv, b2, out, N);
}

// Round 3
// 476.050 us; speedup vs baseline: 1.9614x; 1.1072x over previous
//
#include <hip/hip_runtime.h>

// GCN 2-layer forward on MI355X — CSR gather-aggregation, register-tiled GEMMs.
// d_in: [0]=x (N*128 f32), [1]=edge_index (2*E i32), [2]=W1 (128*64),
//       [3]=b1 (64), [4]=W2 (64*40), [5]=b2 (40)
// d_out: N*40 f32

#define FIN 128
#define H1  64
#define C2  40

// ---------- degree ----------
__global__ void k_count(const int* __restrict__ col, int E, int* __restrict__ deg) {
    int e = blockIdx.x * blockDim.x + threadIdx.x;
    if (e < E) atomicAdd(&deg[col[e]], 1);
}

__global__ void k_dinv(const int* __restrict__ deg, float* __restrict__ dinv, int N) {
    int i = blockIdx.x * blockDim.x + threadIdx.x;
    if (i < N) dinv[i] = rsqrtf((float)deg[i] + 1.0f);  // +1 self-loop
}

// ---------- 3-kernel exclusive scan of deg -> rowptr (cursor = copy) ----------
__global__ __launch_bounds__(256) void k_scanA(const int* __restrict__ deg,
                                               int* __restrict__ rowptr,
                                               int* __restrict__ bsum, int N) {
    __shared__ int s[256];
    int i = blockIdx.x * 256 + threadIdx.x;
    int v = (i < N) ? deg[i] : 0;
    s[threadIdx.x] = v;
    __syncthreads();
    for (int off = 1; off < 256; off <<= 1) {
        int t = (threadIdx.x >= off) ? s[threadIdx.x - off] : 0;
        __syncthreads();
        s[threadIdx.x] += t;
        __syncthreads();
    }
    if (i < N) rowptr[i] = s[threadIdx.x] - v;  // exclusive
    if (threadIdx.x == 255) bsum[blockIdx.x] = s[255];
}

__global__ __launch_bounds__(512) void k_scanB(int* __restrict__ bsum, int nb) {
    __shared__ int s[512];
    int t = threadIdx.x;
    int v = (t < nb) ? bsum[t] : 0;
    s[t] = v;
    __syncthreads();
    for (int off = 1; off < 512; off <<= 1) {
        int u = (t >= off) ? s[t - off] : 0;
        __syncthreads();
        s[t] += u;
        __syncthreads();
    }
    if (t < nb) bsum[t] = s[t] - v;  // exclusive over block sums
}

__global__ void k_scanC(int* __restrict__ rowptr, const int* __restrict__ bsum,
                        int* __restrict__ cursor, int N) {
    int i = blockIdx.x * blockDim.x + threadIdx.x;
    if (i < N) {
        int v = rowptr[i] + bsum[i >> 8];
        rowptr[i] = v;
        cursor[i] = v;   // cursor seeded with rowptr
    }
}

// ---------- CSR fill: esrc[pos] = row (weights computed later from dinv) ----------
__global__ void k_fill(const int* __restrict__ row, const int* __restrict__ col,
                       int* __restrict__ cursor, int* __restrict__ esrc, int E) {
    int e = blockIdx.x * blockDim.x + threadIdx.x;
    if (e >= E) return;
    int r = row[e], c = col[e];
    int pos = atomicAdd(&cursor[c], 1);
    esrc[pos] = r;
}

// ---------- GEMM1: h1 = x @ W1  (N x 128) @ (128 x 64), 64x64 tile, 4x4/thread ----------
__global__ __launch_bounds__(256) void k_gemm1(const float* __restrict__ x,
                                               const float* __restrict__ W1,
                                               float* __restrict__ h1, int N) {
    __shared__ float Ws[FIN * H1];        // 32 KB, layout [k][o]
    __shared__ float xs[64][FIN + 4];     // stride 132: pad for banks, keeps 16B align
    int t = threadIdx.x;
    int node0 = blockIdx.x * 64;

    // stage W1 (2048 float4)
    const float4* W4 = (const float4*)W1;
    float4* Ws4 = (float4*)Ws;
#pragma unroll
    for (int j = 0; j < 8; ++j) Ws4[t + j * 256] = W4[t + j * 256];

    // stage x tile: 64 rows x 128 k = 2048 float4
    const float4* x4 = (const float4*)x;
#pragma unroll
    for (int j = 0; j < 8; ++j) {
        int idx = t + j * 256;
        int r = idx >> 5, kq = idx & 31;           // row, k-quad
        int node = node0 + r; if (node >= N) node = N - 1;
        float4 v = x4[(size_t)node * 32 + kq];
        *(float4*)&xs[r][kq * 4] = v;
    }
    __syncthreads();

    int og = t & 15, ng = t >> 4;
    int o0 = og * 4, n0 = ng * 4;
    float acc[4][4];
#pragma unroll
    for (int i = 0; i < 4; ++i)
#pragma unroll
        for (int j = 0; j < 4; ++j) acc[i][j] = 0.f;

#pragma unroll 8
    for (int k = 0; k < FIN; ++k) {
        float a0 = xs[n0 + 0][k], a1 = xs[n0 + 1][k];
        float a2 = xs[n0 + 2][k], a3 = xs[n0 + 3][k];
        float4 w = *(const float4*)&Ws[k * H1 + o0];
        acc[0][0] += a0 * w.x; acc[0][1] += a0 * w.y; acc[0][2] += a0 * w.z; acc[0][3] += a0 * w.w;
        acc[1][0] += a1 * w.x; acc[1][1] += a1 * w.y; acc[1][2] += a1 * w.z; acc[1][3] += a1 * w.w;
        acc[2][0] += a2 * w.x; acc[2][1] += a2 * w.y; acc[2][2] += a2 * w.z; acc[2][3] += a2 * w.w;
        acc[3][0] += a3 * w.x; acc[3][1] += a3 * w.y; acc[3][2] += a3 * w.z; acc[3][3] += a3 * w.w;
    }

#pragma unroll
    for (int i = 0; i < 4; ++i) {
        int node = node0 + n0 + i;
        if (node < N) {
            float4 v = {acc[i][0], acc[i][1], acc[i][2], acc[i][3]};
            *(float4*)&h1[(size_t)node * H1 + o0] = v;
        }
    }
}

// ---------- agg1: one wave per node, lane = feature (64) ----------
__global__ __launch_bounds__(256) void k_agg1(const int* __restrict__ rowptr,
                                              const int* __restrict__ deg,
                                              const int* __restrict__ esrc,
                                              const float* __restrict__ h1,
                                              const float* __restrict__ dinv,
                                              const float* __restrict__ b1,
                                              float* __restrict__ agg, int N) {
    int w = (blockIdx.x * blockDim.x + threadIdx.x) >> 6;  // node
    int lane = threadIdx.x & 63;
    if (w >= N) return;
    int start = rowptr[w], d = deg[w];
    float dc = dinv[w];
    float acc = dc * dc * h1[(size_t)w * H1 + lane];  // self-loop
    int i = 0;
    for (; i + 4 <= d; i += 4) {
        int e = start + i;
        int r0 = esrc[e], r1 = esrc[e + 1], r2 = esrc[e + 2], r3 = esrc[e + 3];
        float w0 = dinv[r0] * dc, w1 = dinv[r1] * dc;
        float w2 = dinv[r2] * dc, w3 = dinv[r3] * dc;
        float v0 = h1[(size_t)r0 * H1 + lane], v1 = h1[(size_t)r1 * H1 + lane];
        float v2 = h1[(size_t)r2 * H1 + lane], v3 = h1[(size_t)r3 * H1 + lane];
        acc += w0 * v0 + w1 * v1 + w2 * v2 + w3 * v3;
    }
    for (; i < d; ++i) {
        int e = start + i;
        int r = esrc[e];
        acc += dinv[r] * dc * h1[(size_t)r * H1 + lane];
    }
    agg[(size_t)w * H1 + lane] = acc + b1[lane];
}

// ---------- GEMM2: g = relu(agg1) @ W2  (N x 64) @ (64 x 40), 64-node tile ----------
__global__ __launch_bounds__(256) void k_gemm2(const float* __restrict__ agg1,
                                               const float* __restrict__ W2,
                                               float* __restrict__ g, int N) {
    __shared__ float Ws[H1 * C2];        // [k][o] 10 KB
    __shared__ float hs[64][H1 + 4];     // stride 68
    int t = threadIdx.x;
    int node0 = blockIdx.x * 64;

    // stage W2: 2560 floats = 640 float4
    const float4* W4 = (const float4*)W2;
    float4* Ws4 = (float4*)Ws;
    for (int i = t; i < 640; i += 256) Ws4[i] = W4[i];

    // stage relu(agg1) tile: 64 rows x 64 k = 1024 float4
    const float4* a4 = (const float4*)agg1;
#pragma unroll
    for (int j = 0; j < 4; ++j) {
        int idx = t + j * 256;
        int r = idx >> 4, kq = idx & 15;
        int node = node0 + r; if (node >= N) node = N - 1;
        float4 v = a4[(size_t)node * 16 + kq];
        v.x = fmaxf(v.x, 0.f); v.y = fmaxf(v.y, 0.f);
        v.z = fmaxf(v.z, 0.f); v.w = fmaxf(v.w, 0.f);
        *(float4*)&hs[r][kq * 4] = v;
    }
    __syncthreads();

    int og = t & 15, ng = t >> 4;
    int o0 = og * 4, n0 = ng * 4;
    int o0c = (o0 <= 36) ? o0 : 36;     // clamp: lanes with o0>=40 compute garbage, don't store
    float acc[4][4];
#pragma unroll
    for (int i = 0; i < 4; ++i)
#pragma unroll
        for (int j = 0; j < 4; ++j) acc[i][j] = 0.f;

#pragma unroll 8
    for (int k = 0; k < H1; ++k) {
        float a0 = hs[n0 + 0][k], a1 = hs[n0 + 1][k];
        float a2 = hs[n0 + 2][k], a3 = hs[n0 + 3][k];
        float4 w = *(const float4*)&Ws[k * C2 + o0c];
        acc[0][0] += a0 * w.x; acc[0][1] += a0 * w.y; acc[0][2] += a0 * w.z; acc[0][3] += a0 * w.w;
        acc[1][0] += a1 * w.x; acc[1][1] += a1 * w.y; acc[1][2] += a1 * w.z; acc[1][3] += a1 * w.w;
        acc[2][0] += a2 * w.x; acc[2][1] += a2 * w.y; acc[2][2] += a2 * w.z; acc[2][3] += a2 * w.w;
        acc[3][0] += a3 * w.x; acc[3][1] += a3 * w.y; acc[3][2] += a3 * w.z; acc[3][3] += a3 * w.w;
    }

    if (o0 < C2) {
#pragma unroll
        for (int i = 0; i < 4; ++i) {
            int node = node0 + n0 + i;
            if (node < N) {
                float4 v = {acc[i][0], acc[i][1], acc[i][2], acc[i][3]};
                *(float4*)&g[(size_t)node * C2 + o0] = v;
            }
        }
    }
}

// ---------- agg2: one wave per node, lanes 0..39 = features ----------
__global__ __launch_bounds__(256) void k_agg2(const int* __restrict__ rowptr,
                                              const int* __restrict__ deg,
                                              const int* __restrict__ esrc,
                                              const float* __restrict__ g,
                                              const float* __restrict__ dinv,
                                              const float* __restrict__ b2,
                                              float* __restrict__ out, int N) {
    int w = (blockIdx.x * blockDim.x + threadIdx.x) >> 6;  // node
    int lane = threadIdx.x & 63;
    if (w >= N || lane >= C2) return;
    int start = rowptr[w], d = deg[w];
    float dc = dinv[w];
    float acc = dc * dc * g[(size_t)w * C2 + lane];  // self-loop
    int i = 0;
    for (; i + 4 <= d; i += 4) {
        int e = start + i;
        int r0 = esrc[e], r1 = esrc[e + 1], r2 = esrc[e + 2], r3 = esrc[e + 3];
        float w0 = dinv[r0] * dc, w1 = dinv[r1] * dc;
        float w2 = dinv[r2] * dc, w3 = dinv[r3] * dc;
        float v0 = g[(size_t)r0 * C2 + lane], v1 = g[(size_t)r1 * C2 + lane];
        float v2 = g[(size_t)r2 * C2 + lane], v3 = g[(size_t)r3 * C2 + lane];
        acc += w0 * v0 + w1 * v1 + w2 * v2 + w3 * v3;
    }
    for (; i < d; ++i) {
        int e = start + i;
        int r = esrc[e];
        acc += dinv[r] * dc * g[(size_t)r * C2 + lane];
    }
    out[(size_t)w * C2 + lane] = acc + b2[lane];
}

extern "C" void kernel_launch(void* const* d_in, const int* in_sizes, int n_in,
                              void* d_out, int out_size, void* d_ws, size_t ws_size,
                              hipStream_t stream) {
    const float* x   = (const float*)d_in[0];
    const int*   ei  = (const int*)d_in[1];
    const float* W1  = (const float*)d_in[2];
    const float* b1  = (const float*)d_in[3];
    const float* W2  = (const float*)d_in[4];
    const float* b2  = (const float*)d_in[5];
    float* out = (float*)d_out;

    const int N = in_sizes[0] / FIN;       // 100000
    const int E = in_sizes[1] / 2;         // 1600000
    const int* row = ei;
    const int* col = ei + E;

    // workspace layout (4-byte elems)
    char* ws = (char*)d_ws;
    size_t off = 0;
    int*   deg    = (int*)(ws + off);   off += (size_t)N * 4;
    int*   rowptr = (int*)(ws + off);   off += (size_t)N * 4;
    int*   cursor = (int*)(ws + off);   off += (size_t)N * 4;
    int*   bsum   = (int*)(ws + off);   off += 512 * 4;
    float* dinv   = (float*)(ws + off); off += (size_t)N * 4;
    int*   esrc   = (int*)(ws + off);   off += (size_t)E * 4;
    float* h1     = (float*)(ws + off); off += (size_t)N * H1 * 4;
    float* agg1   = (float*)(ws + off); off += (size_t)N * H1 * 4;
    float* g      = (float*)(ws + off); off += (size_t)N * C2 * 4;

    hipMemsetAsync(deg, 0, (size_t)N * sizeof(int), stream);

    k_count<<<(E + 255) / 256, 256, 0, stream>>>(col, E, deg);
    k_dinv<<<(N + 255) / 256, 256, 0, stream>>>(deg, dinv, N);

    // exclusive scan deg -> rowptr; cursor = rowptr
    int nb = (N + 255) / 256;             // 391
    k_scanA<<<nb, 256, 0, stream>>>(deg, rowptr, bsum, N);
    k_scanB<<<1, 512, 0, stream>>>(bsum, nb);
    k_scanC<<<(N + 255) / 256, 256, 0, stream>>>(rowptr, bsum, cursor, N);

    k_fill<<<(E + 255) / 256, 256, 0, stream>>>(row, col, cursor, esrc, E);

    // layer 1
    int gblocks = (N + 63) / 64;          // 1563
    k_gemm1<<<gblocks, 256, 0, stream>>>(x, W1, h1, N);
    k_agg1<<<((size_t)N * 64 + 255) / 256, 256, 0, stream>>>(rowptr, deg, esrc, h1, dinv, b1, agg1, N);

    // layer 2 (ReLU fused into GEMM2 load)
    k_gemm2<<<gblocks, 256, 0, stream>>>(agg1, W2, g, N);
    k_agg2<<<((size_t)N * 64 + 255) / 256, 256, 0, stream>>>(rowptr, deg, esrc, g, dinv, b2, out, N);
}

// Round 4
// 343.157 us; speedup vs baseline: 2.7210x; 1.3873x over previous
//
#include <hip/hip_runtime.h>

// GCN 2-layer forward on MI355X — LDS-staged counting-sort CSR build (no global
// scatter writes), gather aggregation, register-tiled GEMMs.
// d_in: [0]=x (N*128 f32), [1]=edge_index (2*E i32), [2]=W1 (128*64),
//       [3]=b1 (64), [4]=W2 (64*40), [5]=b2 (40)
// d_out: N*40 f32

#define FIN 128
#define H1  64
#define C2  40
#define TILE 8192          // edges per sort tile
#define BCAP 6144          // max edges per 256-dest bucket (mean 4096, sd 64)

// ---------- pass A: per-tile histogram over buckets (bucket = dest >> 8) ----------
__global__ __launch_bounds__(256) void k_hist(const int* __restrict__ col, int E,
                                              int* __restrict__ hist, int NB, int T) {
    extern __shared__ int lh[];          // NB ints
    int t = threadIdx.x, tile = blockIdx.x;
    for (int i = t; i < NB; i += 256) lh[i] = 0;
    __syncthreads();
    int base = tile * TILE;
    int cnt = min(TILE, E - base);
    for (int i = t; i < cnt; i += 256) {
        int c = col[base + i];
        atomicAdd(&lh[c >> 8], 1);
    }
    __syncthreads();
    for (int b = t; b < NB; b += 256) hist[b * T + tile] = lh[b];
}

// ---------- exclusive scan (3 kernels, 512-wide) ----------
__global__ __launch_bounds__(512) void k_scanA(const int* __restrict__ in,
                                               int* __restrict__ out,
                                               int* __restrict__ bsum, int M) {
    __shared__ int s[512];
    int i = blockIdx.x * 512 + threadIdx.x;
    int v = (i < M) ? in[i] : 0;
    s[threadIdx.x] = v;
    __syncthreads();
    for (int off = 1; off < 512; off <<= 1) {
        int u = (threadIdx.x >= off) ? s[threadIdx.x - off] : 0;
        __syncthreads();
        s[threadIdx.x] += u;
        __syncthreads();
    }
    if (i < M) out[i] = s[threadIdx.x] - v;  // exclusive
    if (threadIdx.x == 511) bsum[blockIdx.x] = s[511];
}

__global__ __launch_bounds__(512) void k_scanB(int* __restrict__ bsum, int nb) {
    __shared__ int s[512];
    int t = threadIdx.x;
    int v = (t < nb) ? bsum[t] : 0;
    s[t] = v;
    __syncthreads();
    for (int off = 1; off < 512; off <<= 1) {
        int u = (t >= off) ? s[t - off] : 0;
        __syncthreads();
        s[t] += u;
        __syncthreads();
    }
    if (t < nb) bsum[t] = s[t] - v;
}

__global__ void k_scanC(int* __restrict__ a, const int* __restrict__ bsum, int M) {
    int i = blockIdx.x * blockDim.x + threadIdx.x;
    if (i < M) a[i] += bsum[i >> 9];
}

// ---------- pass B: rank in LDS, stage permuted pairs, coalesced segment writes ----------
__global__ __launch_bounds__(512) void k_scatter(const int* __restrict__ row,
                                                 const int* __restrict__ col,
                                                 const int* __restrict__ scanned,
                                                 int2* __restrict__ pairs,
                                                 int E, int NB, int T) {
    __shared__ int2 stage[TILE];         // 64 KB
    __shared__ int lhist[512];
    __shared__ int loff[512];
    __shared__ int gbase[512];
    int t = threadIdx.x, tile = blockIdx.x;
    int base = tile * TILE;
    int cnt = min(TILE, E - base);

    lhist[t] = 0;
    if (t < NB) gbase[t] = scanned[t * T + tile];
    __syncthreads();

    // local histogram
    for (int i = t; i < cnt; i += 512) {
        int c = col[base + i];
        atomicAdd(&lhist[c >> 8], 1);
    }
    __syncthreads();

    // inclusive scan of lhist -> loff, then convert to exclusive
    loff[t] = lhist[t];
    __syncthreads();
    for (int off = 1; off < 512; off <<= 1) {
        int u = (t >= off) ? loff[t - off] : 0;
        __syncthreads();
        loff[t] += u;
        __syncthreads();
    }
    int ex = loff[t] - lhist[t];
    __syncthreads();
    loff[t] = ex;        // exclusive local offsets
    lhist[t] = ex;       // cursor
    __syncthreads();

    // place into LDS stage at local rank
    for (int i = t; i < cnt; i += 512) {
        int r = row[base + i], c = col[base + i];
        int lpos = atomicAdd(&lhist[c >> 8], 1);
        stage[lpos] = make_int2(r, c);
    }
    __syncthreads();

    // coalesced-ish write: consecutive stage entries of a bucket go to consecutive
    // global addrs at gbase[b] + (i - loff[b])
    for (int i = t; i < cnt; i += 512) {
        int2 p = stage[i];
        int b = p.y >> 8;
        pairs[gbase[b] + (i - loff[b])] = p;
    }
}

// ---------- pass C: per-bucket final sort by dest; writes rowptr/deg/dinv/esrc ----------
__global__ __launch_bounds__(256) void k_bucket(const int2* __restrict__ pairs,
                                                const int* __restrict__ scanned,
                                                int* __restrict__ rowptr,
                                                int* __restrict__ deg,
                                                float* __restrict__ dinv,
                                                int* __restrict__ esrc,
                                                int N, int E, int NB, int T) {
    __shared__ int dcnt[256];
    __shared__ int dloc[256];
    __shared__ int cur[256];
    __shared__ int outbuf[BCAP];         // 24 KB
    int t = threadIdx.x, b = blockIdx.x;
    int d0 = b << 8;
    int nd = min(256, N - d0);
    int bstart = scanned[b * T];
    int bend = (b + 1 < NB) ? scanned[(b + 1) * T] : E;
    int cnt = bend - bstart;

    dcnt[t] = 0;
    __syncthreads();
    for (int i = t; i < cnt; i += 256) {
        int c = pairs[bstart + i].y;
        atomicAdd(&dcnt[c - d0], 1);
    }
    __syncthreads();

    // inclusive scan -> exclusive
    dloc[t] = dcnt[t];
    __syncthreads();
    for (int off = 1; off < 256; off <<= 1) {
        int u = (t >= off) ? dloc[t - off] : 0;
        __syncthreads();
        dloc[t] += u;
        __syncthreads();
    }
    int ex = dloc[t] - dcnt[t];
    __syncthreads();
    dloc[t] = ex;
    cur[t] = ex;
    if (t < nd) {
        int node = d0 + t;
        int dg = dcnt[t];
        rowptr[node] = bstart + ex;
        deg[node] = dg;
        dinv[node] = rsqrtf((float)dg + 1.0f);
    }
    __syncthreads();

    if (cnt <= BCAP) {
        for (int i = t; i < cnt; i += 256) {
            int2 p = pairs[bstart + i];
            int lpos = atomicAdd(&cur[p.y - d0], 1);
            outbuf[lpos] = p.x;
        }
        __syncthreads();
        for (int i = t; i < cnt; i += 256) esrc[bstart + i] = outbuf[i];
    } else {
        // safety fallback (never taken for this input distribution)
        for (int i = t; i < cnt; i += 256) {
            int2 p = pairs[bstart + i];
            int lpos = atomicAdd(&cur[p.y - d0], 1);
            esrc[bstart + lpos] = p.x;
        }
    }
}

// ---------- GEMM1: h1 = x @ W1  (N x 128) @ (128 x 64), 64x64 tile, 4x4/thread ----------
__global__ __launch_bounds__(256) void k_gemm1(const float* __restrict__ x,
                                               const float* __restrict__ W1,
                                               float* __restrict__ h1, int N) {
    __shared__ float Ws[FIN * H1];        // 32 KB, layout [k][o]
    __shared__ float xs[64][FIN + 4];
    int t = threadIdx.x;
    int node0 = blockIdx.x * 64;

    const float4* W4 = (const float4*)W1;
    float4* Ws4 = (float4*)Ws;
#pragma unroll
    for (int j = 0; j < 8; ++j) Ws4[t + j * 256] = W4[t + j * 256];

    const float4* x4 = (const float4*)x;
#pragma unroll
    for (int j = 0; j < 8; ++j) {
        int idx = t + j * 256;
        int r = idx >> 5, kq = idx & 31;
        int node = node0 + r; if (node >= N) node = N - 1;
        float4 v = x4[(size_t)node * 32 + kq];
        *(float4*)&xs[r][kq * 4] = v;
    }
    __syncthreads();

    int og = t & 15, ng = t >> 4;
    int o0 = og * 4, n0 = ng * 4;
    float acc[4][4];
#pragma unroll
    for (int i = 0; i < 4; ++i)
#pragma unroll
        for (int j = 0; j < 4; ++j) acc[i][j] = 0.f;

#pragma unroll 8
    for (int k = 0; k < FIN; ++k) {
        float a0 = xs[n0 + 0][k], a1 = xs[n0 + 1][k];
        float a2 = xs[n0 + 2][k], a3 = xs[n0 + 3][k];
        float4 w = *(const float4*)&Ws[k * H1 + o0];
        acc[0][0] += a0 * w.x; acc[0][1] += a0 * w.y; acc[0][2] += a0 * w.z; acc[0][3] += a0 * w.w;
        acc[1][0] += a1 * w.x; acc[1][1] += a1 * w.y; acc[1][2] += a1 * w.z; acc[1][3] += a1 * w.w;
        acc[2][0] += a2 * w.x; acc[2][1] += a2 * w.y; acc[2][2] += a2 * w.z; acc[2][3] += a2 * w.w;
        acc[3][0] += a3 * w.x; acc[3][1] += a3 * w.y; acc[3][2] += a3 * w.z; acc[3][3] += a3 * w.w;
    }

#pragma unroll
    for (int i = 0; i < 4; ++i) {
        int node = node0 + n0 + i;
        if (node < N) {
            float4 v = {acc[i][0], acc[i][1], acc[i][2], acc[i][3]};
            *(float4*)&h1[(size_t)node * H1 + o0] = v;
        }
    }
}

// ---------- agg1: one wave per node, lane = feature (64) ----------
__global__ __launch_bounds__(256) void k_agg1(const int* __restrict__ rowptr,
                                              const int* __restrict__ deg,
                                              const int* __restrict__ esrc,
                                              const float* __restrict__ h1,
                                              const float* __restrict__ dinv,
                                              const float* __restrict__ b1,
                                              float* __restrict__ agg, int N) {
    int w = (blockIdx.x * blockDim.x + threadIdx.x) >> 6;
    int lane = threadIdx.x & 63;
    if (w >= N) return;
    int start = rowptr[w], d = deg[w];
    float dc = dinv[w];
    float acc = dc * dc * h1[(size_t)w * H1 + lane];
    int i = 0;
    for (; i + 4 <= d; i += 4) {
        int e = start + i;
        int r0 = esrc[e], r1 = esrc[e + 1], r2 = esrc[e + 2], r3 = esrc[e + 3];
        float w0 = dinv[r0] * dc, w1 = dinv[r1] * dc;
        float w2 = dinv[r2] * dc, w3 = dinv[r3] * dc;
        float v0 = h1[(size_t)r0 * H1 + lane], v1 = h1[(size_t)r1 * H1 + lane];
        float v2 = h1[(size_t)r2 * H1 + lane], v3 = h1[(size_t)r3 * H1 + lane];
        acc += w0 * v0 + w1 * v1 + w2 * v2 + w3 * v3;
    }
    for (; i < d; ++i) {
        int r = esrc[start + i];
        acc += dinv[r] * dc * h1[(size_t)r * H1 + lane];
    }
    agg[(size_t)w * H1 + lane] = acc + b1[lane];
}

// ---------- GEMM2: g = relu(agg1) @ W2  (N x 64) @ (64 x 40) ----------
__global__ __launch_bounds__(256) void k_gemm2(const float* __restrict__ agg1,
                                               const float* __restrict__ W2,
                                               float* __restrict__ g, int N) {
    __shared__ float Ws[H1 * C2];
    __shared__ float hs[64][H1 + 4];
    int t = threadIdx.x;
    int node0 = blockIdx.x * 64;

    const float4* W4 = (const float4*)W2;
    float4* Ws4 = (float4*)Ws;
    for (int i = t; i < 640; i += 256) Ws4[i] = W4[i];

    const float4* a4 = (const float4*)agg1;
#pragma unroll
    for (int j = 0; j < 4; ++j) {
        int idx = t + j * 256;
        int r = idx >> 4, kq = idx & 15;
        int node = node0 + r; if (node >= N) node = N - 1;
        float4 v = a4[(size_t)node * 16 + kq];
        v.x = fmaxf(v.x, 0.f); v.y = fmaxf(v.y, 0.f);
        v.z = fmaxf(v.z, 0.f); v.w = fmaxf(v.w, 0.f);
        *(float4*)&hs[r][kq * 4] = v;
    }
    __syncthreads();

    int og = t & 15, ng = t >> 4;
    int o0 = og * 4, n0 = ng * 4;
    int o0c = (o0 <= 36) ? o0 : 36;
    float acc[4][4];
#pragma unroll
    for (int i = 0; i < 4; ++i)
#pragma unroll
        for (int j = 0; j < 4; ++j) acc[i][j] = 0.f;

#pragma unroll 8
    for (int k = 0; k < H1; ++k) {
        float a0 = hs[n0 + 0][k], a1 = hs[n0 + 1][k];
        float a2 = hs[n0 + 2][k], a3 = hs[n0 + 3][k];
        float4 w = *(const float4*)&Ws[k * C2 + o0c];
        acc[0][0] += a0 * w.x; acc[0][1] += a0 * w.y; acc[0][2] += a0 * w.z; acc[0][3] += a0 * w.w;
        acc[1][0] += a1 * w.x; acc[1][1] += a1 * w.y; acc[1][2] += a1 * w.z; acc[1][3] += a1 * w.w;
        acc[2][0] += a2 * w.x; acc[2][1] += a2 * w.y; acc[2][2] += a2 * w.z; acc[2][3] += a2 * w.w;
        acc[3][0] += a3 * w.x; acc[3][1] += a3 * w.y; acc[3][2] += a3 * w.z; acc[3][3] += a3 * w.w;
    }

    if (o0 < C2) {
#pragma unroll
        for (int i = 0; i < 4; ++i) {
            int node = node0 + n0 + i;
            if (node < N) {
                float4 v = {acc[i][0], acc[i][1], acc[i][2], acc[i][3]};
                *(float4*)&g[(size_t)node * C2 + o0] = v;
            }
        }
    }
}

// ---------- agg2: one wave per node, lanes 0..39 = features ----------
__global__ __launch_bounds__(256) void k_agg2(const int* __restrict__ rowptr,
                                              const int* __restrict__ deg,
                                              const int* __restrict__ esrc,
                                              const float* __restrict__ g,
                                              const float* __restrict__ dinv,
                                              const float* __restrict__ b2,
                                              float* __restrict__ out, int N) {
    int w = (blockIdx.x * blockDim.x + threadIdx.x) >> 6;
    int lane = threadIdx.x & 63;
    if (w >= N || lane >= C2) return;
    int start = rowptr[w], d = deg[w];
    float dc = dinv[w];
    float acc = dc * dc * g[(size_t)w * C2 + lane];
    int i = 0;
    for (; i + 4 <= d; i += 4) {
        int e = start + i;
        int r0 = esrc[e], r1 = esrc[e + 1], r2 = esrc[e + 2], r3 = esrc[e + 3];
        float w0 = dinv[r0] * dc, w1 = dinv[r1] * dc;
        float w2 = dinv[r2] * dc, w3 = dinv[r3] * dc;
        float v0 = g[(size_t)r0 * C2 + lane], v1 = g[(size_t)r1 * C2 + lane];
        float v2 = g[(size_t)r2 * C2 + lane], v3 = g[(size_t)r3 * C2 + lane];
        acc += w0 * v0 + w1 * v1 + w2 * v2 + w3 * v3;
    }
    for (; i < d; ++i) {
        int r = esrc[start + i];
        acc += dinv[r] * dc * g[(size_t)r * C2 + lane];
    }
    out[(size_t)w * C2 + lane] = acc + b2[lane];
}

extern "C" void kernel_launch(void* const* d_in, const int* in_sizes, int n_in,
                              void* d_out, int out_size, void* d_ws, size_t ws_size,
                              hipStream_t stream) {
    const float* x   = (const float*)d_in[0];
    const int*   ei  = (const int*)d_in[1];
    const float* W1  = (const float*)d_in[2];
    const float* b1  = (const float*)d_in[3];
    const float* W2  = (const float*)d_in[4];
    const float* b2  = (const float*)d_in[5];
    float* out = (float*)d_out;

    const int N = in_sizes[0] / FIN;       // 100000
    const int E = in_sizes[1] / 2;         // 1600000
    const int* row = ei;
    const int* col = ei + E;

    const int NB = (N + 255) >> 8;         // 391 buckets
    const int T  = (E + TILE - 1) / TILE;  // 196 tiles
    const int M  = NB * T;                 // 76,636 hist entries

    // workspace layout
    char* ws = (char*)d_ws;
    size_t off = 0;
    int*   hist    = (int*)(ws + off);   off += (size_t)M * 4;
    int*   scanned = (int*)(ws + off);   off += (size_t)M * 4;
    int*   bsum    = (int*)(ws + off);   off += 1024 * 4;
    int*   deg     = (int*)(ws + off);   off += (size_t)N * 4;
    int*   rowptr  = (int*)(ws + off);   off += (size_t)N * 4;
    float* dinv    = (float*)(ws + off); off += (size_t)N * 4;
    int2*  pairs   = (int2*)(ws + off);  off += (size_t)E * 8;
    int*   esrc    = (int*)(ws + off);   off += (size_t)E * 4;
    float* h1      = (float*)(ws + off); off += (size_t)N * H1 * 4;
    float* agg1    = (float*)(ws + off); off += (size_t)N * H1 * 4;
    float* g       = (float*)(ws + off); off += (size_t)N * C2 * 4;

    // GEMM1 is independent of the CSR build — run it first to overlap nothing
    // but keep the build's L2 clean for the aggs.
    int gblocks = (N + 63) / 64;
    k_gemm1<<<gblocks, 256, 0, stream>>>(x, W1, h1, N);

    // CSR build (counting sort, no global scatter)
    k_hist<<<T, 256, NB * 4, stream>>>(col, E, hist, NB, T);
    int snb = (M + 511) / 512;             // 150
    k_scanA<<<snb, 512, 0, stream>>>(hist, scanned, bsum, M);
    k_scanB<<<1, 512, 0, stream>>>(bsum, snb);
    k_scanC<<<(M + 255) / 256, 256, 0, stream>>>(scanned, bsum, M);
    k_scatter<<<T, 512, 0, stream>>>(row, col, scanned, pairs, E, NB, T);
    k_bucket<<<NB, 256, 0, stream>>>(pairs, scanned, rowptr, deg, dinv, esrc, N, E, NB, T);

    // layer 1 aggregation
    k_agg1<<<((size_t)N * 64 + 255) / 256, 256, 0, stream>>>(rowptr, deg, esrc, h1, dinv, b1, agg1, N);

    // layer 2
    k_gemm2<<<gblocks, 256, 0, stream>>>(agg1, W2, g, N);
    k_agg2<<<((size_t)N * 64 + 255) / 256, 256, 0, stream>>>(rowptr, deg, esrc, g, dinv, b2, out, N);
}

// Round 5
// 316.926 us; speedup vs baseline: 2.9462x; 1.0828x over previous
//
#include <hip/hip_runtime.h>
#include <hip/hip_fp16.h>

// GCN 2-layer forward on MI355X — counting-sort CSR build (packed pairs),
// fp16 line-aligned gather arrays, register-tiled GEMMs, fp32 accumulation.
// d_in: [0]=x (N*128 f32), [1]=edge_index (2*E i32), [2]=W1 (128*64),
//       [3]=b1 (64), [4]=W2 (64*40), [5]=b2 (40)
// d_out: N*40 f32

#define FIN 128
#define H1  64
#define C2  40
#define GP  64            // padded row stride (halves) for g => 128 B lines
#define TILE 8192         // edges per sort tile
#define BCAP 6144         // max edges per 256-dest bucket (mean 4096, sd 64)

// ---------- pass A: per-tile histogram over buckets (bucket = dest >> 8) ----------
__global__ __launch_bounds__(256) void k_hist(const int* __restrict__ col, int E,
                                              int* __restrict__ hist, int NB, int T) {
    extern __shared__ int lh[];          // NB ints
    int t = threadIdx.x, tile = blockIdx.x;
    for (int i = t; i < NB; i += 256) lh[i] = 0;
    __syncthreads();
    int base = tile * TILE;
    int cnt = min(TILE, E - base);
    for (int i = t; i < cnt; i += 256) {
        int c = col[base + i];
        atomicAdd(&lh[c >> 8], 1);
    }
    __syncthreads();
    for (int b = t; b < NB; b += 256) hist[b * T + tile] = lh[b];
}

// ---------- exclusive scan (3 kernels, 512-wide) ----------
__global__ __launch_bounds__(512) void k_scanA(const int* __restrict__ in,
                                               int* __restrict__ out,
                                               int* __restrict__ bsum, int M) {
    __shared__ int s[512];
    int i = blockIdx.x * 512 + threadIdx.x;
    int v = (i < M) ? in[i] : 0;
    s[threadIdx.x] = v;
    __syncthreads();
    for (int off = 1; off < 512; off <<= 1) {
        int u = (threadIdx.x >= off) ? s[threadIdx.x - off] : 0;
        __syncthreads();
        s[threadIdx.x] += u;
        __syncthreads();
    }
    if (i < M) out[i] = s[threadIdx.x] - v;  // exclusive
    if (threadIdx.x == 511) bsum[blockIdx.x] = s[511];
}

__global__ __launch_bounds__(512) void k_scanB(int* __restrict__ bsum, int nb) {
    __shared__ int s[512];
    int t = threadIdx.x;
    int v = (t < nb) ? bsum[t] : 0;
    s[t] = v;
    __syncthreads();
    for (int off = 1; off < 512; off <<= 1) {
        int u = (t >= off) ? s[t - off] : 0;
        __syncthreads();
        s[t] += u;
        __syncthreads();
    }
    if (t < nb) bsum[t] = s[t] - v;
}

__global__ void k_scanC(int* __restrict__ a, const int* __restrict__ bsum, int M) {
    int i = blockIdx.x * blockDim.x + threadIdx.x;
    if (i < M) a[i] += bsum[i >> 9];
}

// ---------- pass B: rank in LDS, stage, write packed pairs per bucket-segment ----------
// packed pair: bits 0..23 = src row, bits 24..31 = dest low 8 bits
__global__ __launch_bounds__(512) void k_scatter(const int* __restrict__ row,
                                                 const int* __restrict__ col,
                                                 const int* __restrict__ scanned,
                                                 int* __restrict__ pairs,
                                                 int E, int NB, int T) {
    __shared__ int2 stage[TILE];         // 64 KB
    __shared__ int lhist[512];
    __shared__ int loff[512];
    __shared__ int gbase[512];
    int t = threadIdx.x, tile = blockIdx.x;
    int base = tile * TILE;
    int cnt = min(TILE, E - base);

    lhist[t] = 0;
    if (t < NB) gbase[t] = scanned[t * T + tile];
    __syncthreads();

    for (int i = t; i < cnt; i += 512) {
        int c = col[base + i];
        atomicAdd(&lhist[c >> 8], 1);
    }
    __syncthreads();

    loff[t] = lhist[t];
    __syncthreads();
    for (int off = 1; off < 512; off <<= 1) {
        int u = (t >= off) ? loff[t - off] : 0;
        __syncthreads();
        loff[t] += u;
        __syncthreads();
    }
    int ex = loff[t] - lhist[t];
    __syncthreads();
    loff[t] = ex;
    lhist[t] = ex;
    __syncthreads();

    for (int i = t; i < cnt; i += 512) {
        int r = row[base + i], c = col[base + i];
        int lpos = atomicAdd(&lhist[c >> 8], 1);
        stage[lpos] = make_int2(r, c);
    }
    __syncthreads();

    for (int i = t; i < cnt; i += 512) {
        int2 p = stage[i];
        int b = p.y >> 8;
        pairs[gbase[b] + (i - loff[b])] = p.x | ((p.y & 255) << 24);
    }
}

// ---------- pass C: per-bucket sort by dest; writes rowptr/deg/dinv/esrc ----------
__global__ __launch_bounds__(256) void k_bucket(const int* __restrict__ pairs,
                                                const int* __restrict__ scanned,
                                                int* __restrict__ rowptr,
                                                int* __restrict__ deg,
                                                float* __restrict__ dinv,
                                                int* __restrict__ esrc,
                                                int N, int E, int NB, int T) {
    __shared__ int dcnt[256];
    __shared__ int cur[256];
    __shared__ int outbuf[BCAP];         // 24 KB
    int t = threadIdx.x, b = blockIdx.x;
    int d0 = b << 8;
    int nd = min(256, N - d0);
    int bstart = scanned[b * T];
    int bend = (b + 1 < NB) ? scanned[(b + 1) * T] : E;
    int cnt = bend - bstart;

    dcnt[t] = 0;
    __syncthreads();
    for (int i = t; i < cnt; i += 256) {
        unsigned p = (unsigned)pairs[bstart + i];
        atomicAdd(&dcnt[p >> 24], 1);
    }
    __syncthreads();

    // inclusive scan -> exclusive
    int myc = dcnt[t];
    cur[t] = myc;
    __syncthreads();
    for (int off = 1; off < 256; off <<= 1) {
        int u = (t >= off) ? cur[t - off] : 0;
        __syncthreads();
        cur[t] += u;
        __syncthreads();
    }
    int ex = cur[t] - myc;
    __syncthreads();
    cur[t] = ex;
    if (t < nd) {
        int node = d0 + t;
        rowptr[node] = bstart + ex;
        deg[node] = myc;
        dinv[node] = rsqrtf((float)myc + 1.0f);
    }
    __syncthreads();

    if (cnt <= BCAP) {
        for (int i = t; i < cnt; i += 256) {
            unsigned p = (unsigned)pairs[bstart + i];
            int lpos = atomicAdd(&cur[p >> 24], 1);
            outbuf[lpos] = (int)(p & 0xFFFFFF);
        }
        __syncthreads();
        for (int i = t; i < cnt; i += 256) esrc[bstart + i] = outbuf[i];
    } else {
        for (int i = t; i < cnt; i += 256) {
            unsigned p = (unsigned)pairs[bstart + i];
            int lpos = atomicAdd(&cur[p >> 24], 1);
            esrc[bstart + lpos] = (int)(p & 0xFFFFFF);
        }
    }
}

// ---------- GEMM1: h1 = fp16(x @ W1)  (N x 128)@(128 x 64), 64x64 tile ----------
__global__ __launch_bounds__(256) void k_gemm1(const float* __restrict__ x,
                                               const float* __restrict__ W1,
                                               __half* __restrict__ h1, int N) {
    __shared__ float Ws[FIN * H1];        // 32 KB, [k][o]
    __shared__ float xs[64][FIN + 4];
    int t = threadIdx.x;
    int node0 = blockIdx.x * 64;

    const float4* W4 = (const float4*)W1;
    float4* Ws4 = (float4*)Ws;
#pragma unroll
    for (int j = 0; j < 8; ++j) Ws4[t + j * 256] = W4[t + j * 256];

    const float4* x4 = (const float4*)x;
#pragma unroll
    for (int j = 0; j < 8; ++j) {
        int idx = t + j * 256;
        int r = idx >> 5, kq = idx & 31;
        int node = node0 + r; if (node >= N) node = N - 1;
        float4 v = x4[(size_t)node * 32 + kq];
        *(float4*)&xs[r][kq * 4] = v;
    }
    __syncthreads();

    int og = t & 15, ng = t >> 4;
    int o0 = og * 4, n0 = ng * 4;
    float acc[4][4];
#pragma unroll
    for (int i = 0; i < 4; ++i)
#pragma unroll
        for (int j = 0; j < 4; ++j) acc[i][j] = 0.f;

#pragma unroll 8
    for (int k = 0; k < FIN; ++k) {
        float a0 = xs[n0 + 0][k], a1 = xs[n0 + 1][k];
        float a2 = xs[n0 + 2][k], a3 = xs[n0 + 3][k];
        float4 w = *(const float4*)&Ws[k * H1 + o0];
        acc[0][0] += a0 * w.x; acc[0][1] += a0 * w.y; acc[0][2] += a0 * w.z; acc[0][3] += a0 * w.w;
        acc[1][0] += a1 * w.x; acc[1][1] += a1 * w.y; acc[1][2] += a1 * w.z; acc[1][3] += a1 * w.w;
        acc[2][0] += a2 * w.x; acc[2][1] += a2 * w.y; acc[2][2] += a2 * w.z; acc[2][3] += a2 * w.w;
        acc[3][0] += a3 * w.x; acc[3][1] += a3 * w.y; acc[3][2] += a3 * w.z; acc[3][3] += a3 * w.w;
    }

#pragma unroll
    for (int i = 0; i < 4; ++i) {
        int node = node0 + n0 + i;
        if (node < N) {
            union { __half h[4]; uint2 u; } pk;
            pk.h[0] = __float2half_rn(acc[i][0]);
            pk.h[1] = __float2half_rn(acc[i][1]);
            pk.h[2] = __float2half_rn(acc[i][2]);
            pk.h[3] = __float2half_rn(acc[i][3]);
            *(uint2*)&h1[(size_t)node * H1 + o0] = pk.u;
        }
    }
}

// ---------- agg1: one wave per node, lane = feature; fp16 gather, fp32 acc ----------
__global__ __launch_bounds__(256) void k_agg1(const int* __restrict__ rowptr,
                                              const int* __restrict__ deg,
                                              const int* __restrict__ esrc,
                                              const __half* __restrict__ h1,
                                              const float* __restrict__ dinv,
                                              const float* __restrict__ b1,
                                              float* __restrict__ agg, int N) {
    int w = (blockIdx.x * blockDim.x + threadIdx.x) >> 6;
    int lane = threadIdx.x & 63;
    if (w >= N) return;
    int start = rowptr[w], d = deg[w];
    float dc = dinv[w];
    float acc = dc * dc * __half2float(h1[(size_t)w * H1 + lane]);
    int i = 0;
    for (; i + 4 <= d; i += 4) {
        int e = start + i;
        int r0 = esrc[e], r1 = esrc[e + 1], r2 = esrc[e + 2], r3 = esrc[e + 3];
        float w0 = dinv[r0] * dc, w1 = dinv[r1] * dc;
        float w2 = dinv[r2] * dc, w3 = dinv[r3] * dc;
        float v0 = __half2float(h1[(size_t)r0 * H1 + lane]);
        float v1 = __half2float(h1[(size_t)r1 * H1 + lane]);
        float v2 = __half2float(h1[(size_t)r2 * H1 + lane]);
        float v3 = __half2float(h1[(size_t)r3 * H1 + lane]);
        acc += w0 * v0 + w1 * v1 + w2 * v2 + w3 * v3;
    }
    for (; i < d; ++i) {
        int r = esrc[start + i];
        acc += dinv[r] * dc * __half2float(h1[(size_t)r * H1 + lane]);
    }
    agg[(size_t)w * H1 + lane] = acc + b1[lane];
}

// ---------- GEMM2: g = fp16(relu(agg1) @ W2), padded row stride GP=64 ----------
__global__ __launch_bounds__(256) void k_gemm2(const float* __restrict__ agg1,
                                               const float* __restrict__ W2,
                                               __half* __restrict__ g, int N) {
    __shared__ float Ws[H1 * C2];
    __shared__ float hs[64][H1 + 4];
    int t = threadIdx.x;
    int node0 = blockIdx.x * 64;

    const float4* W4 = (const float4*)W2;
    float4* Ws4 = (float4*)Ws;
    for (int i = t; i < 640; i += 256) Ws4[i] = W4[i];

    const float4* a4 = (const float4*)agg1;
#pragma unroll
    for (int j = 0; j < 4; ++j) {
        int idx = t + j * 256;
        int r = idx >> 4, kq = idx & 15;
        int node = node0 + r; if (node >= N) node = N - 1;
        float4 v = a4[(size_t)node * 16 + kq];
        v.x = fmaxf(v.x, 0.f); v.y = fmaxf(v.y, 0.f);
        v.z = fmaxf(v.z, 0.f); v.w = fmaxf(v.w, 0.f);
        *(float4*)&hs[r][kq * 4] = v;
    }
    __syncthreads();

    int og = t & 15, ng = t >> 4;
    int o0 = og * 4, n0 = ng * 4;
    int o0c = (o0 <= 36) ? o0 : 36;
    float acc[4][4];
#pragma unroll
    for (int i = 0; i < 4; ++i)
#pragma unroll
        for (int j = 0; j < 4; ++j) acc[i][j] = 0.f;

#pragma unroll 8
    for (int k = 0; k < H1; ++k) {
        float a0 = hs[n0 + 0][k], a1 = hs[n0 + 1][k];
        float a2 = hs[n0 + 2][k], a3 = hs[n0 + 3][k];
        float4 w = *(const float4*)&Ws[k * C2 + o0c];
        acc[0][0] += a0 * w.x; acc[0][1] += a0 * w.y; acc[0][2] += a0 * w.z; acc[0][3] += a0 * w.w;
        acc[1][0] += a1 * w.x; acc[1][1] += a1 * w.y; acc[1][2] += a1 * w.z; acc[1][3] += a1 * w.w;
        acc[2][0] += a2 * w.x; acc[2][1] += a2 * w.y; acc[2][2] += a2 * w.z; acc[2][3] += a2 * w.w;
        acc[3][0] += a3 * w.x; acc[3][1] += a3 * w.y; acc[3][2] += a3 * w.z; acc[3][3] += a3 * w.w;
    }

    if (o0 < C2) {
#pragma unroll
        for (int i = 0; i < 4; ++i) {
            int node = node0 + n0 + i;
            if (node < N) {
                union { __half h[4]; uint2 u; } pk;
                pk.h[0] = __float2half_rn(acc[i][0]);
                pk.h[1] = __float2half_rn(acc[i][1]);
                pk.h[2] = __float2half_rn(acc[i][2]);
                pk.h[3] = __float2half_rn(acc[i][3]);
                *(uint2*)&g[(size_t)node * GP + o0] = pk.u;
            }
        }
    }
}

// ---------- agg2: one wave per node, lanes 0..39; fp16 line-aligned gather ----------
__global__ __launch_bounds__(256) void k_agg2(const int* __restrict__ rowptr,
                                              const int* __restrict__ deg,
                                              const int* __restrict__ esrc,
                                              const __half* __restrict__ g,
                                              const float* __restrict__ dinv,
                                              const float* __restrict__ b2,
                                              float* __restrict__ out, int N) {
    int w = (blockIdx.x * blockDim.x + threadIdx.x) >> 6;
    int lane = threadIdx.x & 63;
    if (w >= N || lane >= C2) return;
    int start = rowptr[w], d = deg[w];
    float dc = dinv[w];
    float acc = dc * dc * __half2float(g[(size_t)w * GP + lane]);
    int i = 0;
    for (; i + 4 <= d; i += 4) {
        int e = start + i;
        int r0 = esrc[e], r1 = esrc[e + 1], r2 = esrc[e + 2], r3 = esrc[e + 3];
        float w0 = dinv[r0] * dc, w1 = dinv[r1] * dc;
        float w2 = dinv[r2] * dc, w3 = dinv[r3] * dc;
        float v0 = __half2float(g[(size_t)r0 * GP + lane]);
        float v1 = __half2float(g[(size_t)r1 * GP + lane]);
        float v2 = __half2float(g[(size_t)r2 * GP + lane]);
        float v3 = __half2float(g[(size_t)r3 * GP + lane]);
        acc += w0 * v0 + w1 * v1 + w2 * v2 + w3 * v3;
    }
    for (; i < d; ++i) {
        int r = esrc[start + i];
        acc += dinv[r] * dc * __half2float(g[(size_t)r * GP + lane]);
    }
    out[(size_t)w * C2 + lane] = acc + b2[lane];
}

extern "C" void kernel_launch(void* const* d_in, const int* in_sizes, int n_in,
                              void* d_out, int out_size, void* d_ws, size_t ws_size,
                              hipStream_t stream) {
    const float* x   = (const float*)d_in[0];
    const int*   ei  = (const int*)d_in[1];
    const float* W1  = (const float*)d_in[2];
    const float* b1  = (const float*)d_in[3];
    const float* W2  = (const float*)d_in[4];
    const float* b2  = (const float*)d_in[5];
    float* out = (float*)d_out;

    const int N = in_sizes[0] / FIN;       // 100000
    const int E = in_sizes[1] / 2;         // 1600000
    const int* row = ei;
    const int* col = ei + E;

    const int NB = (N + 255) >> 8;         // 391 buckets
    const int T  = (E + TILE - 1) / TILE;  // 196 tiles
    const int M  = NB * T;                 // 76,636 hist entries

    // workspace layout
    char* ws = (char*)d_ws;
    size_t off = 0;
    int*    hist    = (int*)(ws + off);    off += (size_t)M * 4;
    int*    scanned = (int*)(ws + off);    off += (size_t)M * 4;
    int*    bsum    = (int*)(ws + off);    off += 1024 * 4;
    int*    deg     = (int*)(ws + off);    off += (size_t)N * 4;
    int*    rowptr  = (int*)(ws + off);    off += (size_t)N * 4;
    float*  dinv    = (float*)(ws + off);  off += (size_t)N * 4;
    int*    pairs   = (int*)(ws + off);    off += (size_t)E * 4;
    int*    esrc    = (int*)(ws + off);    off += (size_t)E * 4;
    __half* h1      = (__half*)(ws + off); off += (size_t)N * H1 * 2;
    float*  agg1    = (float*)(ws + off);  off += (size_t)N * H1 * 4;
    __half* g       = (__half*)(ws + off); off += (size_t)N * GP * 2;

    int gblocks = (N + 63) / 64;
    k_gemm1<<<gblocks, 256, 0, stream>>>(x, W1, h1, N);

    // CSR build (counting sort, packed pairs)
    k_hist<<<T, 256, NB * 4, stream>>>(col, E, hist, NB, T);
    int snb = (M + 511) / 512;             // 150
    k_scanA<<<snb, 512, 0, stream>>>(hist, scanned, bsum, M);
    k_scanB<<<1, 512, 0, stream>>>(bsum, snb);
    k_scanC<<<(M + 255) / 256, 256, 0, stream>>>(scanned, bsum, M);
    k_scatter<<<T, 512, 0, stream>>>(row, col, scanned, pairs, E, NB, T);
    k_bucket<<<NB, 256, 0, stream>>>(pairs, scanned, rowptr, deg, dinv, esrc, N, E, NB, T);

    // layer 1 aggregation
    k_agg1<<<((size_t)N * 64 + 255) / 256, 256, 0, stream>>>(rowptr, deg, esrc, h1, dinv, b1, agg1, N);

    // layer 2
    k_gemm2<<<gblocks, 256, 0, stream>>>(agg1, W2, g, N);
    k_agg2<<<((size_t)N * 64 + 255) / 256, 256, 0, stream>>>(rowptr, deg, esrc, g, dinv, b2, out, N);
}